// Round 1
// baseline (1239.960 us; speedup 1.0000x reference)
//
#include <hip/hip_runtime.h>
#include <math.h>

// Problem constants
#define B_ 32
#define D_ 192
#define DEPTH_ 4
#define DI_ 384
#define DS_ 16
#define DC_ 4
#define P_ 16
#define IMG_ 224
#define N_ 196
#define L_ 197

__device__ __forceinline__ float sigmoidf_(float x) { return 1.f / (1.f + expf(-x)); }

// ---------------- cls token + pos embed (row l=0) ----------------
__global__ void k_cls(const float* __restrict__ cls_tok, const float* __restrict__ pos,
                      float* __restrict__ t) {
  int b = blockIdx.x, d = threadIdx.x;
  t[(size_t)b * L_ * D_ + d] = cls_tok[d] + pos[d];
}

// ---------------- patch embed: block = (b, h-row of patches), 14 tokens ----------------
__global__ __launch_bounds__(192) void k_patch(const float* __restrict__ x,
                                               const float* __restrict__ pw,
                                               const float* __restrict__ pb,
                                               const float* __restrict__ pos,
                                               float* __restrict__ t) {
  __shared__ __align__(16) float p_s[14 * 768];
  int b = blockIdx.x / 14;
  int h = blockIdx.x % 14;
  int tid = threadIdx.x;
  // stage 14 patches: iterate 48 image rows (c,i); each row has 224 consecutive pixels
  for (int r = 0; r < 48; r++) {
    int c = r >> 4, i = r & 15;
    const float* rowp = x + ((size_t)(b * 3 + c) * 224 + h * 16 + i) * 224;
    for (int f = tid; f < 224; f += 192) {
      int m = f >> 4, jj = f & 15;
      p_s[m * 768 + c * 256 + i * 16 + jj] = rowp[f];
    }
  }
  __syncthreads();
  float acc[14];
#pragma unroll
  for (int m = 0; m < 14; m++) acc[m] = 0.f;
  const float* wrow = pw + (size_t)tid * 768;
  for (int k = 0; k < 768; k += 4) {
    float4 wv = *(const float4*)(wrow + k);
#pragma unroll
    for (int m = 0; m < 14; m++) {
      float4 a = *(const float4*)(p_s + m * 768 + k);
      acc[m] = fmaf(a.x, wv.x, fmaf(a.y, wv.y, fmaf(a.z, wv.z, fmaf(a.w, wv.w, acc[m]))));
    }
  }
  float pbv = pb[tid];
#pragma unroll
  for (int m = 0; m < 14; m++) {
    int p = h * 14 + m;
    t[((size_t)b * L_ + 1 + p) * D_ + tid] = acc[m] + pbv + pos[(size_t)(1 + p) * D_ + tid];
  }
}

// ---------------- LayerNorm per token: 64 threads, 192 elems ----------------
__global__ __launch_bounds__(64) void k_ln(const float* __restrict__ t,
                                           const float* __restrict__ g,
                                           const float* __restrict__ bb,
                                           float* __restrict__ o) {
  int tok = blockIdx.x, tid = threadIdx.x;
  const float* xr = t + (size_t)tok * D_;
  float x0 = xr[tid], x1 = xr[tid + 64], x2 = xr[tid + 128];
  float s = x0 + x1 + x2;
  float q = x0 * x0 + x1 * x1 + x2 * x2;
#pragma unroll
  for (int off = 1; off < 64; off <<= 1) {
    s += __shfl_xor(s, off, 64);
    q += __shfl_xor(q, off, 64);
  }
  float m = s * (1.f / 192.f);
  float r = rsqrtf(q * (1.f / 192.f) - m * m + 1e-5f);
  float* orow = o + (size_t)tok * D_;
  orow[tid]       = (x0 - m) * r * g[tid]       + bb[tid];
  orow[tid + 64]  = (x1 - m) * r * g[tid + 64]  + bb[tid + 64];
  orow[tid + 128] = (x2 - m) * r * g[tid + 128] + bb[tid + 128];
}

// ---------------- xz = xln @ w_in^T : M=6304(=394*16), K=192, N=768 ----------------
__global__ __launch_bounds__(256) void k_gemm_in(const float* __restrict__ a,
                                                 const float* __restrict__ w,
                                                 float* __restrict__ c) {
  __shared__ __align__(16) float a_s[16 * 192];
  int tile = blockIdx.x, tid = threadIdx.x;
  const float* ar = a + (size_t)tile * 16 * 192;
  for (int f = tid; f < 3072; f += 256) a_s[f] = ar[f];
  __syncthreads();
  float acc0[16], acc1[16], acc2[16];
#pragma unroll
  for (int m = 0; m < 16; m++) acc0[m] = acc1[m] = acc2[m] = 0.f;
  const float* w0 = w + (size_t)tid * 192;
  const float* w1 = w + (size_t)(tid + 256) * 192;
  const float* w2 = w + (size_t)(tid + 512) * 192;
  for (int k = 0; k < 192; k += 4) {
    float4 v0 = *(const float4*)(w0 + k);
    float4 v1 = *(const float4*)(w1 + k);
    float4 v2 = *(const float4*)(w2 + k);
#pragma unroll
    for (int m = 0; m < 16; m++) {
      float4 av = *(const float4*)(a_s + m * 192 + k);
      acc0[m] = fmaf(av.x, v0.x, fmaf(av.y, v0.y, fmaf(av.z, v0.z, fmaf(av.w, v0.w, acc0[m]))));
      acc1[m] = fmaf(av.x, v1.x, fmaf(av.y, v1.y, fmaf(av.z, v1.z, fmaf(av.w, v1.w, acc1[m]))));
      acc2[m] = fmaf(av.x, v2.x, fmaf(av.y, v2.y, fmaf(av.z, v2.z, fmaf(av.w, v2.w, acc2[m]))));
    }
  }
#pragma unroll
  for (int m = 0; m < 16; m++) {
    float* crow = c + ((size_t)tile * 16 + m) * 768;
    crow[tid] = acc0[m];
    crow[tid + 256] = acc1[m];
    crow[tid + 512] = acc2[m];
  }
}

// ---------------- causal depthwise conv (DC=4) + silu -> xa ; silu(z) -> sz ----------------
__global__ __launch_bounds__(384) void k_conv(const float* __restrict__ xz,
                                              const float* __restrict__ cw_,
                                              const float* __restrict__ cb,
                                              float* __restrict__ xa,
                                              float* __restrict__ sz) {
  int row = blockIdx.x;  // b*L + l
  int l = row % L_;
  int d = threadIdx.x;
  float4 cw = *(const float4*)(cw_ + d * 4);
  const float* xc = xz + (size_t)row * 768 + d;
  float acc = cb[d];
  acc = fmaf(cw.w, xc[0], acc);
  if (l >= 1) acc = fmaf(cw.z, xc[-768], acc);
  if (l >= 2) acc = fmaf(cw.y, xc[-2 * 768], acc);
  if (l >= 3) acc = fmaf(cw.x, xc[-3 * 768], acc);
  xa[(size_t)row * DI_ + d] = acc * sigmoidf_(acc);
  float z = xc[384];
  sz[(size_t)row * DI_ + d] = z * sigmoidf_(z);
}

// ---------------- bcd = xa @ w_x^T (N=33) ; fused dt = softplus(bcd[32]*w_dt+b_dt) ----------------
__global__ __launch_bounds__(256) void k_bcd(const float* __restrict__ xa,
                                             const float* __restrict__ w_x,
                                             const float* __restrict__ w_dt,
                                             const float* __restrict__ b_dt,
                                             float* __restrict__ bcd,
                                             float* __restrict__ dt) {
  __shared__ __align__(16) float xs[4][384];
  int wv = threadIdx.x >> 6, lane = threadIdx.x & 63;
  int tok = blockIdx.x * 4 + wv;
  const float* xr = xa + (size_t)tok * DI_;
  for (int f = lane; f < 384; f += 64) xs[wv][f] = xr[f];
  float a = 0.f;
  if (lane < 33) {
    const float* wrow = w_x + lane * 384;
#pragma unroll 4
    for (int k = 0; k < 384; k += 4) {
      float4 xv = *(const float4*)(&xs[wv][k]);
      float4 ww = *(const float4*)(wrow + k);
      a = fmaf(xv.x, ww.x, a);
      a = fmaf(xv.y, ww.y, a);
      a = fmaf(xv.z, ww.z, a);
      a = fmaf(xv.w, ww.w, a);
    }
    bcd[(size_t)tok * 33 + lane] = a;
  }
  float dtraw = __shfl(a, 32, 64);
#pragma unroll
  for (int j = 0; j < 6; j++) {
    int d = lane + j * 64;
    float v = fmaf(dtraw, w_dt[d], b_dt[d]);
    dt[(size_t)tok * DI_ + d] = (v > 20.f) ? v : log1pf(expf(v));
  }
}

// ---------------- selective scan: block = 16 d x 16 n ; serial over L ----------------
__global__ __launch_bounds__(256) void k_scan(const float* __restrict__ bcd,
                                              const float* __restrict__ dt,
                                              const float* __restrict__ xa,
                                              const float* __restrict__ sz,
                                              const float* __restrict__ A_log,
                                              const float* __restrict__ D_ssm,
                                              float* __restrict__ y) {
  int b = blockIdx.x / 24, chunk = blockIdx.x % 24;
  int tid = threadIdx.x;
  int dl = tid >> 4, n = tid & 15;
  int d = chunk * 16 + dl;
  float Av = -expf(A_log[d * 16 + n]);
  float Dv = D_ssm[d];
  const float* bcd_b = bcd + (size_t)b * L_ * 33;
  const float* dt_b = dt + (size_t)b * L_ * DI_ + d;
  const float* xa_b = xa + (size_t)b * L_ * DI_ + d;
  const float* sz_b = sz + (size_t)b * L_ * DI_ + d;
  float* y_b = y + (size_t)b * L_ * DI_ + d;
  float h = 0.f;
  for (int l0 = 0; l0 < L_; l0 += 8) {
    float Bn[8], Cn[8], dtv[8], xv[8], szv[8];
#pragma unroll
    for (int j = 0; j < 8; j++) {
      int l = l0 + j;
      if (l < L_) {
        Bn[j] = bcd_b[l * 33 + n];
        Cn[j] = bcd_b[l * 33 + 16 + n];
        dtv[j] = dt_b[(size_t)l * DI_];
        xv[j] = xa_b[(size_t)l * DI_];
        if (n == 0) szv[j] = sz_b[(size_t)l * DI_];
      }
    }
#pragma unroll
    for (int j = 0; j < 8; j++) {
      int l = l0 + j;
      if (l < L_) {
        float dA = expf(dtv[j] * Av);
        h = fmaf(dA, h, dtv[j] * Bn[j] * xv[j]);
        float c = h * Cn[j];
        c += __shfl_xor(c, 1, 16);
        c += __shfl_xor(c, 2, 16);
        c += __shfl_xor(c, 4, 16);
        c += __shfl_xor(c, 8, 16);
        if (n == 0) y_b[(size_t)l * DI_] = fmaf(xv[j], Dv, c) * szv[j];
      }
    }
  }
}

// ---------------- t += y @ w_out^T : M=6304, K=384, N=192 ----------------
__global__ __launch_bounds__(192) void k_gemm_out(const float* __restrict__ a,
                                                  const float* __restrict__ w,
                                                  float* __restrict__ t) {
  __shared__ __align__(16) float a_s[16 * 384];
  int tile = blockIdx.x, tid = threadIdx.x;
  const float* ar = a + (size_t)tile * 16 * 384;
  for (int f = tid; f < 6144; f += 192) a_s[f] = ar[f];
  __syncthreads();
  float acc[16];
#pragma unroll
  for (int m = 0; m < 16; m++) acc[m] = 0.f;
  const float* wrow = w + (size_t)tid * 384;
  for (int k = 0; k < 384; k += 4) {
    float4 wv = *(const float4*)(wrow + k);
#pragma unroll
    for (int m = 0; m < 16; m++) {
      float4 av = *(const float4*)(a_s + m * 384 + k);
      acc[m] = fmaf(av.x, wv.x, fmaf(av.y, wv.y, fmaf(av.z, wv.z, fmaf(av.w, wv.w, acc[m]))));
    }
  }
#pragma unroll
  for (int m = 0; m < 16; m++) {
    size_t idx = ((size_t)tile * 16 + m) * D_ + tid;
    t[idx] += acc[m];
  }
}

// ---------------- final LN(token 0) + cls head + reg head ----------------
__global__ __launch_bounds__(192) void k_head(const float* __restrict__ t,
                                              const float* __restrict__ fn_g,
                                              const float* __restrict__ fn_b,
                                              const float* __restrict__ cls_w,
                                              const float* __restrict__ cls_b,
                                              const float* __restrict__ rw1,
                                              const float* __restrict__ rb1,
                                              const float* __restrict__ rw2,
                                              const float* __restrict__ rb2,
                                              float* __restrict__ out) {
  __shared__ float red[8];
  __shared__ float stats[2];
  __shared__ float feat_s[192];
  __shared__ float h_s[96];
  int b = blockIdx.x, tid = threadIdx.x;
  float x = t[(size_t)b * L_ * D_ + tid];
  float s = x, q = x * x;
#pragma unroll
  for (int off = 1; off < 64; off <<= 1) {
    s += __shfl_xor(s, off, 64);
    q += __shfl_xor(q, off, 64);
  }
  int w = tid >> 6;
  if ((tid & 63) == 0) { red[w] = s; red[4 + w] = q; }
  __syncthreads();
  if (tid == 0) {
    float ss = red[0] + red[1] + red[2];
    float qq = red[4] + red[5] + red[6];
    float m = ss * (1.f / 192.f);
    stats[0] = m;
    stats[1] = rsqrtf(qq * (1.f / 192.f) - m * m + 1e-5f);
  }
  __syncthreads();
  float fv = (x - stats[0]) * stats[1] * fn_g[tid] + fn_b[tid];
  feat_s[tid] = fv;
  __syncthreads();
  if (tid < 96) {
    float a = rb1[tid];
    const float* wr = rw1 + (size_t)tid * 192;
    for (int k = 0; k < 192; k++) a = fmaf(feat_s[k], wr[k], a);
    // exact GELU
    h_s[tid] = 0.5f * a * (1.f + erff(a * 0.70710678118654752f));
  } else if (tid < 98) {
    int c = tid - 96;
    float a = cls_b[c];
    const float* wr = cls_w + (size_t)c * 192;
    for (int k = 0; k < 192; k++) a = fmaf(feat_s[k], wr[k], a);
    out[b * 2 + c] = a;
  }
  __syncthreads();
  if (tid == 0) {
    float a = rb2[0];
    for (int j = 0; j < 96; j++) a = fmaf(h_s[j], rw2[j], a);
    out[64 + b] = a;
  }
}

extern "C" void kernel_launch(void* const* d_in, const int* in_sizes, int n_in,
                              void* d_out, int out_size, void* d_ws, size_t ws_size,
                              hipStream_t stream) {
  const float* x       = (const float*)d_in[0];
  const float* patch_w = (const float*)d_in[1];
  const float* patch_b = (const float*)d_in[2];
  const float* cls_tok = (const float*)d_in[3];
  const float* pos     = (const float*)d_in[4];
  const float* ln_g    = (const float*)d_in[5];
  const float* ln_b    = (const float*)d_in[6];
  const float* w_in    = (const float*)d_in[7];
  const float* conv_w  = (const float*)d_in[8];
  const float* conv_b  = (const float*)d_in[9];
  const float* w_x     = (const float*)d_in[10];
  const float* w_dt    = (const float*)d_in[11];
  const float* b_dt    = (const float*)d_in[12];
  const float* A_log   = (const float*)d_in[13];
  const float* D_ssm   = (const float*)d_in[14];
  const float* w_out   = (const float*)d_in[15];
  const float* fn_g    = (const float*)d_in[16];
  const float* fn_b    = (const float*)d_in[17];
  const float* cls_w   = (const float*)d_in[18];
  const float* cls_b   = (const float*)d_in[19];
  const float* reg_w1  = (const float*)d_in[20];
  const float* reg_b1  = (const float*)d_in[21];
  const float* reg_w2  = (const float*)d_in[22];
  const float* reg_b2  = (const float*)d_in[23];
  float* out = (float*)d_out;

  float* ws = (float*)d_ws;
  // workspace layout (floats)
  float* t_buf = ws;                       // B*L*D       = 1211904
  float* xln   = t_buf + 1211904;          // B*L*D       = 1211904
  float* xz    = xln + 1211904;            // B*L*768     = 4847616
  float* xa    = xz + 4847616;             // B*L*384     = 2423808
  float* szb   = xa + 2423808;             // B*L*384     = 2423808
  float* bcd   = szb + 2423808;            // B*L*33      = 208032
  float* dtb   = bcd + 208032;             // B*L*384     = 2423808
  float* yb    = dtb + 2423808;            // B*L*384     = 2423808

  k_cls<<<32, 192, 0, stream>>>(cls_tok, pos, t_buf);
  k_patch<<<448, 192, 0, stream>>>(x, patch_w, patch_b, pos, t_buf);
  for (int i = 0; i < DEPTH_; i++) {
    k_ln<<<B_ * L_, 64, 0, stream>>>(t_buf, ln_g + i * D_, ln_b + i * D_, xln);
    k_gemm_in<<<394, 256, 0, stream>>>(xln, w_in + (size_t)i * 768 * D_, xz);
    k_conv<<<B_ * L_, 384, 0, stream>>>(xz, conv_w + i * DI_ * DC_, conv_b + i * DI_, xa, szb);
    k_bcd<<<1576, 256, 0, stream>>>(xa, w_x + i * 33 * DI_, w_dt + i * DI_, b_dt + i * DI_, bcd, dtb);
    k_scan<<<768, 256, 0, stream>>>(bcd, dtb, xa, szb, A_log + i * DI_ * DS_, D_ssm + i * DI_, yb);
    k_gemm_out<<<394, 192, 0, stream>>>(yb, w_out + (size_t)i * D_ * DI_, t_buf);
  }
  k_head<<<32, 192, 0, stream>>>(t_buf, fn_g, fn_b, cls_w, cls_b, reg_w1, reg_b1,
                                 reg_w2, reg_b2, out);
}